// Round 1
// baseline (1231.876 us; speedup 1.0000x reference)
//
#include <hip/hip_runtime.h>
#include <math.h>

#define EPS 1e-4f

// dims (fixed by setup_inputs)
// B=2, T=2048, D=1024, HEADS=16, DH=64
// tokens M = 4096, E = 4096, BH = 32

// ---------------------------------------------------------------------------
// GEMM1: P[m][e] = sum_d X[m][d] * Win[e][d] + bin[e]
// scatter: e = h*256 + part*64 + j
//   part 0 (Q), 1 (K): transposed layout  [bh][j][t]   (bh = b*16+h)
//   part 2 (V), 3 (G): natural layout     [bh][t][j]
// ---------------------------------------------------------------------------
__global__ __launch_bounds__(256)
void sga_gemm1(const float* __restrict__ X, const float* __restrict__ Win,
               const float* __restrict__ bin,
               float* __restrict__ Qt, float* __restrict__ Kt,
               float* __restrict__ Vv, float* __restrict__ Gg)
{
    __shared__ float As[16][132];
    __shared__ float Bs[16][132];
    const int tid = threadIdx.x;
    const int tx = tid & 15, ty = tid >> 4;
    const int m0 = blockIdx.y * 128, n0 = blockIdx.x * 128;
    const int lrow = tid >> 2, lc4 = tid & 3;

    float acc[2][2][4][4] = {};

    for (int k0 = 0; k0 < 1024; k0 += 16) {
        float4 a0 = *(const float4*)&X[(m0 + lrow) * 1024 + k0 + lc4 * 4];
        float4 a1 = *(const float4*)&X[(m0 + 64 + lrow) * 1024 + k0 + lc4 * 4];
        float4 b0 = *(const float4*)&Win[(n0 + lrow) * 1024 + k0 + lc4 * 4];
        float4 b1 = *(const float4*)&Win[(n0 + 64 + lrow) * 1024 + k0 + lc4 * 4];
        __syncthreads();
        As[lc4*4+0][lrow] = a0.x; As[lc4*4+1][lrow] = a0.y;
        As[lc4*4+2][lrow] = a0.z; As[lc4*4+3][lrow] = a0.w;
        As[lc4*4+0][64+lrow] = a1.x; As[lc4*4+1][64+lrow] = a1.y;
        As[lc4*4+2][64+lrow] = a1.z; As[lc4*4+3][64+lrow] = a1.w;
        Bs[lc4*4+0][lrow] = b0.x; Bs[lc4*4+1][lrow] = b0.y;
        Bs[lc4*4+2][lrow] = b0.z; Bs[lc4*4+3][lrow] = b0.w;
        Bs[lc4*4+0][64+lrow] = b1.x; Bs[lc4*4+1][64+lrow] = b1.y;
        Bs[lc4*4+2][64+lrow] = b1.z; Bs[lc4*4+3][64+lrow] = b1.w;
        __syncthreads();
        #pragma unroll
        for (int kk = 0; kk < 16; ++kk) {
            float4 av0 = *(const float4*)&As[kk][ty * 4];
            float4 av1 = *(const float4*)&As[kk][64 + ty * 4];
            float4 bv0 = *(const float4*)&Bs[kk][tx * 4];
            float4 bv1 = *(const float4*)&Bs[kk][64 + tx * 4];
            float am[8] = {av0.x, av0.y, av0.z, av0.w, av1.x, av1.y, av1.z, av1.w};
            float bn[8] = {bv0.x, bv0.y, bv0.z, bv0.w, bv1.x, bv1.y, bv1.z, bv1.w};
            #pragma unroll
            for (int mg = 0; mg < 2; ++mg)
            #pragma unroll
            for (int mi = 0; mi < 4; ++mi)
            #pragma unroll
            for (int ng = 0; ng < 2; ++ng)
            #pragma unroll
            for (int ni = 0; ni < 4; ++ni)
                acc[mg][ng][mi][ni] += am[mg * 4 + mi] * bn[ng * 4 + ni];
        }
    }

    #pragma unroll
    for (int mg = 0; mg < 2; ++mg)
    #pragma unroll
    for (int ng = 0; ng < 2; ++ng) {
        const int e0   = n0 + ng * 64 + tx * 4;
        const int tok0 = m0 + mg * 64 + ty * 4;
        const int h = e0 >> 8, c = e0 & 255;
        const int part = c >> 6, j0 = c & 63;
        const int bb = tok0 >> 11, tloc = tok0 & 2047;
        const int bhi = bb * 16 + h;
        float bz[4] = {bin[e0], bin[e0 + 1], bin[e0 + 2], bin[e0 + 3]};
        if (part < 2) {
            float* dst = (part == 0) ? Qt : Kt;
            #pragma unroll
            for (int ni = 0; ni < 4; ++ni) {
                float4 v = make_float4(acc[mg][ng][0][ni] + bz[ni],
                                       acc[mg][ng][1][ni] + bz[ni],
                                       acc[mg][ng][2][ni] + bz[ni],
                                       acc[mg][ng][3][ni] + bz[ni]);
                *(float4*)&dst[(bhi * 64 + j0 + ni) * 2048 + tloc] = v;
            }
        } else {
            float* dst = (part == 2) ? Vv : Gg;
            #pragma unroll
            for (int mi = 0; mi < 4; ++mi) {
                float4 v = make_float4(acc[mg][ng][mi][0] + bz[0],
                                       acc[mg][ng][mi][1] + bz[1],
                                       acc[mg][ng][mi][2] + bz[2],
                                       acc[mg][ng][mi][3] + bz[3]);
                *(float4*)&dst[(bhi * 2048 + tloc + mi) * 64 + j0] = v;
            }
        }
    }
}

// ---------------------------------------------------------------------------
// q2/k2 norms from transposed Q,K: q2s[bh][t] = sum_dd Qt[bh][dd][t]^2
// ---------------------------------------------------------------------------
__global__ __launch_bounds__(256)
void sga_norms(const float* __restrict__ Qt, const float* __restrict__ Kt,
               float* __restrict__ q2s, float* __restrict__ k2s)
{
    const int bh = blockIdx.y;
    const int t  = blockIdx.x * 256 + threadIdx.x;
    const float* qb = Qt + (bh * 64) * 2048 + t;
    const float* kb = Kt + (bh * 64) * 2048 + t;
    float sq = 0.f, sk = 0.f;
    #pragma unroll 8
    for (int dd = 0; dd < 64; ++dd) {
        float q = qb[dd * 2048]; sq += q * q;
        float k = kb[dd * 2048]; sk += k * k;
    }
    q2s[bh * 2048 + t] = sq;
    k2s[bh * 2048 + t] = sk;
}

// ---------------------------------------------------------------------------
// Attention: per (bh, 64-q-row tile). Single pass over k tiles of 64.
//   phase A: S = Q.K^T (from LDS, both stored [dd][row]) -> shepard weights
//            Ws[k][q] (transposed for phase B) + row-sum partials
//   phase B: acc[q][dh] += Ws * V
//   epilogue: A = acc/(EPS+sumw); H[token][h*64+dh] = G * A
// ---------------------------------------------------------------------------
__global__ __launch_bounds__(256)
void sga_attn(const float* __restrict__ Qt, const float* __restrict__ Kt,
              const float* __restrict__ Vv, const float* __restrict__ Gg,
              const float* __restrict__ q2s, const float* __restrict__ k2s,
              float* __restrict__ H)
{
    __shared__ float Qs[64][68];
    __shared__ float Ks[64][68];
    __shared__ float Vs[64][68];
    __shared__ float Ws[64][68];
    __shared__ float Pp[64][20];
    __shared__ float Sw[64];

    const int tid = threadIdx.x;
    const int tx = tid & 15, ty = tid >> 4;
    const int bh = blockIdx.y;
    const int q0 = blockIdx.x * 64;
    const int ldd = tid >> 2, lc = tid & 3;

    // load Q tile [dd][q0..q0+63]
    {
        const float* src = Qt + (bh * 64 + ldd) * 2048 + q0;
        #pragma unroll
        for (int i = 0; i < 4; ++i)
            *(float4*)&Qs[ldd][(lc + i * 4) * 4] = *(const float4*)&src[(lc + i * 4) * 4];
    }
    if (tid < 64) Sw[tid] = 0.f;

    float rq2[4];
    #pragma unroll
    for (int i = 0; i < 4; ++i) rq2[i] = q2s[bh * 2048 + q0 + ty * 4 + i];

    float acc[4][4] = {};

    for (int kt = 0; kt < 32; ++kt) {
        const int k0 = kt * 64;
        // prefetch K,V tiles into regs
        float4 kv[4], vvr[4];
        const float* ksrc = Kt + (bh * 64 + ldd) * 2048 + k0;
        const float* vsrc = Vv + (bh * 2048 + k0 + ldd) * 64;
        #pragma unroll
        for (int i = 0; i < 4; ++i) {
            kv[i]  = *(const float4*)&ksrc[(lc + i * 4) * 4];
            vvr[i] = *(const float4*)&vsrc[(lc + i * 4) * 4];
        }
        float k2r[4];
        #pragma unroll
        for (int j = 0; j < 4; ++j) k2r[j] = k2s[bh * 2048 + k0 + tx * 4 + j];

        __syncthreads();   // prev phase B done with Ks/Vs
        #pragma unroll
        for (int i = 0; i < 4; ++i) {
            *(float4*)&Ks[ldd][(lc + i * 4) * 4] = kv[i];
            *(float4*)&Vs[ldd][(lc + i * 4) * 4] = vvr[i];
        }
        __syncthreads();

        // phase A: S[q][k], q = ty*4+i, k = tx*4+j
        float s[4][4] = {};
        #pragma unroll 16
        for (int dd = 0; dd < 64; ++dd) {
            float4 a = *(const float4*)&Qs[dd][ty * 4];
            float4 b = *(const float4*)&Ks[dd][tx * 4];
            float av[4] = {a.x, a.y, a.z, a.w};
            float bv[4] = {b.x, b.y, b.z, b.w};
            #pragma unroll
            for (int i = 0; i < 4; ++i)
            #pragma unroll
            for (int j = 0; j < 4; ++j)
                s[i][j] += av[i] * bv[j];
        }
        // shepard weights
        float wv[4][4];
        #pragma unroll
        for (int i = 0; i < 4; ++i)
        #pragma unroll
        for (int j = 0; j < 4; ++j) {
            float d2 = rq2[i] + k2r[j] - 2.f * s[i][j];
            d2 = fmaxf(d2, 0.f);
            float dist = sqrtf(d2);
            float u = EPS + dist;
            wv[i][j] = 1.0f / (u * u);
        }
        // store transposed Ws[k][q] + row partials
        #pragma unroll
        for (int j = 0; j < 4; ++j)
            *(float4*)&Ws[tx * 4 + j][ty * 4] =
                make_float4(wv[0][j], wv[1][j], wv[2][j], wv[3][j]);
        #pragma unroll
        for (int i = 0; i < 4; ++i)
            Pp[ty * 4 + i][tx] = wv[i][0] + wv[i][1] + wv[i][2] + wv[i][3];
        __syncthreads();

        // row-sum accumulate
        if (tid < 64) {
            const float4* p = (const float4*)&Pp[tid][0];
            float4 p0 = p[0], p1 = p[1], p2 = p[2], p3 = p[3];
            Sw[tid] += p0.x + p0.y + p0.z + p0.w + p1.x + p1.y + p1.z + p1.w +
                       p2.x + p2.y + p2.z + p2.w + p3.x + p3.y + p3.z + p3.w;
        }

        // phase B: acc[q][dh] += W[q][k] * V[k][dh]
        #pragma unroll 16
        for (int k = 0; k < 64; ++k) {
            float4 aw = *(const float4*)&Ws[k][ty * 4];
            float4 bv = *(const float4*)&Vs[k][tx * 4];
            float av[4] = {aw.x, aw.y, aw.z, aw.w};
            float vb[4] = {bv.x, bv.y, bv.z, bv.w};
            #pragma unroll
            for (int i = 0; i < 4; ++i)
            #pragma unroll
            for (int j = 0; j < 4; ++j)
                acc[i][j] += av[i] * vb[j];
        }
    }
    __syncthreads();

    // epilogue: normalize, gate, store H[token][h*64+dh]
    const int bb = bh >> 4, h = bh & 15;
    #pragma unroll
    for (int i = 0; i < 4; ++i) {
        const int t = q0 + ty * 4 + i;
        const float inv = 1.0f / (EPS + Sw[ty * 4 + i]);
        float4 g = *(const float4*)&Gg[(bh * 2048 + t) * 64 + tx * 4];
        float4 o;
        o.x = acc[i][0] * inv * g.x;
        o.y = acc[i][1] * inv * g.y;
        o.z = acc[i][2] * inv * g.z;
        o.w = acc[i][3] * inv * g.w;
        *(float4*)&H[(bb * 2048 + t) * 1024 + h * 64 + tx * 4] = o;
    }
}

// ---------------------------------------------------------------------------
// GEMM2: Y[m][n] = sum_e H[m][e] * Wout[n][e] + bout[n]
// ---------------------------------------------------------------------------
__global__ __launch_bounds__(256)
void sga_gemm2(const float* __restrict__ Hh, const float* __restrict__ Wout,
               const float* __restrict__ bout, float* __restrict__ Y)
{
    __shared__ float As[16][132];
    __shared__ float Bs[16][132];
    const int tid = threadIdx.x;
    const int tx = tid & 15, ty = tid >> 4;
    const int m0 = blockIdx.y * 128, n0 = blockIdx.x * 128;
    const int lrow = tid >> 2, lc4 = tid & 3;

    float acc[2][2][4][4] = {};

    for (int k0 = 0; k0 < 1024; k0 += 16) {
        float4 a0 = *(const float4*)&Hh[(m0 + lrow) * 1024 + k0 + lc4 * 4];
        float4 a1 = *(const float4*)&Hh[(m0 + 64 + lrow) * 1024 + k0 + lc4 * 4];
        float4 b0 = *(const float4*)&Wout[(n0 + lrow) * 1024 + k0 + lc4 * 4];
        float4 b1 = *(const float4*)&Wout[(n0 + 64 + lrow) * 1024 + k0 + lc4 * 4];
        __syncthreads();
        As[lc4*4+0][lrow] = a0.x; As[lc4*4+1][lrow] = a0.y;
        As[lc4*4+2][lrow] = a0.z; As[lc4*4+3][lrow] = a0.w;
        As[lc4*4+0][64+lrow] = a1.x; As[lc4*4+1][64+lrow] = a1.y;
        As[lc4*4+2][64+lrow] = a1.z; As[lc4*4+3][64+lrow] = a1.w;
        Bs[lc4*4+0][lrow] = b0.x; Bs[lc4*4+1][lrow] = b0.y;
        Bs[lc4*4+2][lrow] = b0.z; Bs[lc4*4+3][lrow] = b0.w;
        Bs[lc4*4+0][64+lrow] = b1.x; Bs[lc4*4+1][64+lrow] = b1.y;
        Bs[lc4*4+2][64+lrow] = b1.z; Bs[lc4*4+3][64+lrow] = b1.w;
        __syncthreads();
        #pragma unroll
        for (int kk = 0; kk < 16; ++kk) {
            float4 av0 = *(const float4*)&As[kk][ty * 4];
            float4 av1 = *(const float4*)&As[kk][64 + ty * 4];
            float4 bv0 = *(const float4*)&Bs[kk][tx * 4];
            float4 bv1 = *(const float4*)&Bs[kk][64 + tx * 4];
            float am[8] = {av0.x, av0.y, av0.z, av0.w, av1.x, av1.y, av1.z, av1.w};
            float bn[8] = {bv0.x, bv0.y, bv0.z, bv0.w, bv1.x, bv1.y, bv1.z, bv1.w};
            #pragma unroll
            for (int mg = 0; mg < 2; ++mg)
            #pragma unroll
            for (int mi = 0; mi < 4; ++mi)
            #pragma unroll
            for (int ng = 0; ng < 2; ++ng)
            #pragma unroll
            for (int ni = 0; ni < 4; ++ni)
                acc[mg][ng][mi][ni] += am[mg * 4 + mi] * bn[ng * 4 + ni];
        }
    }

    #pragma unroll
    for (int mg = 0; mg < 2; ++mg)
    #pragma unroll
    for (int ng = 0; ng < 2; ++ng) {
        const int n = n0 + ng * 64 + tx * 4;
        const int m = m0 + mg * 64 + ty * 4;
        float4 bz = *(const float4*)&bout[n];
        #pragma unroll
        for (int mi = 0; mi < 4; ++mi) {
            float4 v = make_float4(acc[mg][ng][mi][0] + bz.x,
                                   acc[mg][ng][mi][1] + bz.y,
                                   acc[mg][ng][mi][2] + bz.z,
                                   acc[mg][ng][mi][3] + bz.w);
            *(float4*)&Y[(m + mi) * 1024 + n] = v;
        }
    }
}

extern "C" void kernel_launch(void* const* d_in, const int* in_sizes, int n_in,
                              void* d_out, int out_size, void* d_ws, size_t ws_size,
                              hipStream_t stream) {
    const float* X    = (const float*)d_in[0];
    const float* Win  = (const float*)d_in[1];
    const float* bin  = (const float*)d_in[2];
    const float* Wout = (const float*)d_in[3];
    const float* bout = (const float*)d_in[4];
    float* Y = (float*)d_out;

    float* ws = (float*)d_ws;
    const int PER = 32 * 2048 * 64;   // 4,194,304 floats per tensor
    float* Qt  = ws;
    float* Kt  = Qt + PER;
    float* Vv  = Kt + PER;
    float* Gg  = Vv + PER;
    float* Hh  = Gg + PER;
    float* q2s = Hh + PER;
    float* k2s = q2s + 32 * 2048;

    sga_gemm1<<<dim3(32, 32), 256, 0, stream>>>(X, Win, bin, Qt, Kt, Vv, Gg);
    sga_norms<<<dim3(8, 32), 256, 0, stream>>>(Qt, Kt, q2s, k2s);
    sga_attn <<<dim3(32, 32), 256, 0, stream>>>(Qt, Kt, Vv, Gg, q2s, k2s, Hh);
    sga_gemm2<<<dim3(8, 32), 256, 0, stream>>>(Hh, Wout, bout, Y);
}

// Round 2
// 327.910 us; speedup vs baseline: 3.7568x; 3.7568x over previous
//
#include <hip/hip_runtime.h>
#include <math.h>

#define EPS 1e-4f

// dims: B=2, T=2048, D=1024, HEADS=16, DH=64, E=4096, TOK=4096, BH=32

typedef __attribute__((ext_vector_type(8))) short bf16x8;
typedef __attribute__((ext_vector_type(4))) float f32x4;

#define MFMA(a, b, c) __builtin_amdgcn_mfma_f32_16x16x32_bf16(a, b, c, 0, 0, 0)

__device__ __forceinline__ unsigned short f2b(float f) {
    unsigned int u = __float_as_uint(f);
    u += 0x7fffu + ((u >> 16) & 1u);   // RNE
    return (unsigned short)(u >> 16);
}
__device__ __forceinline__ float b2f(unsigned short u) {
    return __uint_as_float(((unsigned int)u) << 16);
}

// ---------------------------------------------------------------------------
// fp32 -> bf16 convert (vectorized, grid-stride). n8 = elements/8.
// ---------------------------------------------------------------------------
__global__ __launch_bounds__(256)
void sga_f2b(const float* __restrict__ src, unsigned short* __restrict__ dst, int n8) {
    int i = blockIdx.x * 256 + threadIdx.x;
    const int stride = gridDim.x * 256;
    for (; i < n8; i += stride) {
        const float4* s = (const float4*)src + i * 2;
        float4 a = s[0], b = s[1];
        uint4 o;
        o.x = (unsigned)f2b(a.x) | ((unsigned)f2b(a.y) << 16);
        o.y = (unsigned)f2b(a.z) | ((unsigned)f2b(a.w) << 16);
        o.z = (unsigned)f2b(b.x) | ((unsigned)f2b(b.y) << 16);
        o.w = (unsigned)f2b(b.z) | ((unsigned)f2b(b.w) << 16);
        *((uint4*)dst + i) = o;
    }
}

// ---------------------------------------------------------------------------
// GEMM1 (bf16 MFMA, 128x128 tile, BK=32): P = Xb * Winb^T + bin, scattered:
//   e = h*256 + part*64 + j ; part 0=Q,1=K,3=G natural [bh][t][64] bf16
//   part 2=V transposed [bh][64][t] bf16
// ---------------------------------------------------------------------------
__global__ __launch_bounds__(256)
void sga_gemm1(const unsigned short* __restrict__ Xb, const unsigned short* __restrict__ Wb,
               const float* __restrict__ bin,
               unsigned short* __restrict__ Qb, unsigned short* __restrict__ Kb,
               unsigned short* __restrict__ Vt, unsigned short* __restrict__ Gb)
{
    __shared__ unsigned short As[128 * 40];
    __shared__ unsigned short Bs[128 * 40];
    const int tid = threadIdx.x;
    const int lane = tid & 63, w = tid >> 6;
    const int lr = lane & 15, lg = lane >> 4;
    const int wm = w & 1, wn = w >> 1;
    const int m0 = blockIdx.y * 128, n0 = blockIdx.x * 128;
    const int r0 = tid >> 2, c0 = tid & 3;

    const unsigned short* Ap = Xb + (m0 + r0) * 1024 + c0 * 8;
    const unsigned short* Bp = Wb + (n0 + r0) * 1024 + c0 * 8;
    bf16x8 pa0 = *(const bf16x8*)Ap;
    bf16x8 pa1 = *(const bf16x8*)(Ap + 64 * 1024);
    bf16x8 pb0 = *(const bf16x8*)Bp;
    bf16x8 pb1 = *(const bf16x8*)(Bp + 64 * 1024);
    unsigned short* Aw = &As[r0 * 40 + c0 * 8];
    unsigned short* Bw = &Bs[r0 * 40 + c0 * 8];

    f32x4 acc[4][4] = {};

    for (int kt = 0; kt < 32; ++kt) {
        __syncthreads();
        *(bf16x8*)Aw = pa0; *(bf16x8*)(Aw + 64 * 40) = pa1;
        *(bf16x8*)Bw = pb0; *(bf16x8*)(Bw + 64 * 40) = pb1;
        __syncthreads();
        if (kt < 31) {
            Ap += 32; Bp += 32;
            pa0 = *(const bf16x8*)Ap; pa1 = *(const bf16x8*)(Ap + 64 * 1024);
            pb0 = *(const bf16x8*)Bp; pb1 = *(const bf16x8*)(Bp + 64 * 1024);
        }
        bf16x8 af[4], bfr[4];
        #pragma unroll
        for (int i = 0; i < 4; ++i)
            af[i] = *(const bf16x8*)&As[(wm * 64 + i * 16 + lr) * 40 + lg * 8];
        #pragma unroll
        for (int i = 0; i < 4; ++i)
            bfr[i] = *(const bf16x8*)&Bs[(wn * 64 + i * 16 + lr) * 40 + lg * 8];
        #pragma unroll
        for (int mi = 0; mi < 4; ++mi)
            #pragma unroll
            for (int ni = 0; ni < 4; ++ni)
                acc[mi][ni] = MFMA(af[mi], bfr[ni], acc[mi][ni]);
    }

    // epilogue scatter
    const int bb = m0 >> 11;
    #pragma unroll
    for (int mf = 0; mf < 4; ++mf) {
        const int tbase = m0 + wm * 64 + mf * 16 + lg * 4;
        const int tloc = tbase & 2047;
        #pragma unroll
        for (int nf = 0; nf < 4; ++nf) {
            const int n = n0 + wn * 64 + nf * 16 + lr;
            const int h = n >> 8, cc = n & 255;
            const int part = cc >> 6, j = cc & 63;
            const int bh = bb * 16 + h;
            const float bz = bin[n];
            f32x4 v = acc[mf][nf];
            unsigned short e0 = f2b(v[0] + bz), e1 = f2b(v[1] + bz),
                           e2 = f2b(v[2] + bz), e3 = f2b(v[3] + bz);
            if (part == 2) {
                ushort4 pk = make_ushort4(e0, e1, e2, e3);
                *(ushort4*)&Vt[(bh * 64 + j) * 2048 + tloc] = pk;
            } else {
                unsigned short* dst = (part == 0) ? Qb : ((part == 1) ? Kb : Gb);
                unsigned short vv[4] = {e0, e1, e2, e3};
                #pragma unroll
                for (int r = 0; r < 4; ++r)
                    dst[(bh * 2048 + tloc + r) * 64 + j] = vv[r];
            }
        }
    }
}

// ---------------------------------------------------------------------------
// fp32 row norms of the bf16-rounded Q,K (self-consistent with MFMA QK^T)
// ---------------------------------------------------------------------------
__global__ __launch_bounds__(256)
void sga_norms(const unsigned short* __restrict__ Qb, const unsigned short* __restrict__ Kb,
               float* __restrict__ q2s, float* __restrict__ k2s)
{
    const int idx = blockIdx.x * 256 + threadIdx.x;  // 0..65535 = bh*2048+t
    const unsigned short* q = Qb + idx * 64;
    const unsigned short* k = Kb + idx * 64;
    float sq = 0.f, sk = 0.f;
    #pragma unroll
    for (int c = 0; c < 8; ++c) {
        bf16x8 a = *(const bf16x8*)(q + c * 8);
        bf16x8 b = *(const bf16x8*)(k + c * 8);
        #pragma unroll
        for (int e = 0; e < 8; ++e) {
            float f = b2f((unsigned short)a[e]); sq += f * f;
            float g = b2f((unsigned short)b[e]); sk += g * g;
        }
    }
    q2s[idx] = sq;
    k2s[idx] = sk;
}

// ---------------------------------------------------------------------------
// Attention, MFMA. Block = 4 waves, 64 q-rows (16 per wave). No __syncthreads:
// K/V read direct from global (L1/L2-resident), W re-fragmented through a
// per-wave private padded LDS slab.
// ---------------------------------------------------------------------------
__global__ __launch_bounds__(256)
void sga_attn(const unsigned short* __restrict__ Qb, const unsigned short* __restrict__ Kb,
              const unsigned short* __restrict__ Vt, const unsigned short* __restrict__ Gb,
              const float* __restrict__ q2s, const float* __restrict__ k2s,
              unsigned short* __restrict__ Hb)
{
    __shared__ unsigned short Wlds[4 * 16 * 72];
    const int tid = threadIdx.x;
    const int lane = tid & 63, w = tid >> 6;
    const int lr = lane & 15, lg = lane >> 4;
    const int bh = blockIdx.y;
    const int q0 = blockIdx.x * 64 + w * 16;
    unsigned short* wl = &Wlds[w * 16 * 72];

    const unsigned short* qp = Qb + (bh * 2048 + q0 + lr) * 64 + lg * 8;
    bf16x8 qa0 = *(const bf16x8*)qp;
    bf16x8 qa1 = *(const bf16x8*)(qp + 32);
    float q2v[4];
    #pragma unroll
    for (int r = 0; r < 4; ++r) q2v[r] = q2s[bh * 2048 + q0 + lg * 4 + r];

    f32x4 oacc[4] = {};
    float sumw[4] = {0.f, 0.f, 0.f, 0.f};

    for (int kt = 0; kt < 32; ++kt) {
        const int k0 = kt * 64;
        // QK^T: S[q 16][k 64]
        f32x4 sa[4] = {};
        #pragma unroll
        for (int nf = 0; nf < 4; ++nf) {
            const unsigned short* kp = Kb + (bh * 2048 + k0 + nf * 16 + lr) * 64 + lg * 8;
            bf16x8 b0 = *(const bf16x8*)kp;
            bf16x8 b1 = *(const bf16x8*)(kp + 32);
            sa[nf] = MFMA(qa0, b0, sa[nf]);
            sa[nf] = MFMA(qa1, b1, sa[nf]);
        }
        // Shepard weights + row-sum partials; stash bf16 W into wave LDS
        float rs[4] = {0.f, 0.f, 0.f, 0.f};
        #pragma unroll
        for (int nf = 0; nf < 4; ++nf) {
            const float k2 = k2s[bh * 2048 + k0 + nf * 16 + lr];
            #pragma unroll
            for (int r = 0; r < 4; ++r) {
                float d2 = q2v[r] + k2 - 2.0f * sa[nf][r];
                d2 = fmaxf(d2, 0.0f);
                float u = EPS + __builtin_amdgcn_sqrtf(d2);
                float rc = __builtin_amdgcn_rcpf(u);
                float wv = rc * rc;
                rs[r] += wv;
                wl[(lg * 4 + r) * 72 + nf * 16 + lr] = f2b(wv);
            }
        }
        // reduce row sums across the 16 k-lanes
        #pragma unroll
        for (int m = 1; m < 16; m <<= 1) {
            #pragma unroll
            for (int r = 0; r < 4; ++r) rs[r] += __shfl_xor(rs[r], m, 64);
        }
        #pragma unroll
        for (int r = 0; r < 4; ++r) sumw[r] += rs[r];

        // re-fragment W as MFMA A-operand
        bf16x8 pa0 = *(const bf16x8*)&wl[lr * 72 + lg * 8];
        bf16x8 pa1 = *(const bf16x8*)&wl[lr * 72 + 32 + lg * 8];
        // PV: acc[q 16][dh 64]
        #pragma unroll
        for (int vf = 0; vf < 4; ++vf) {
            const unsigned short* vp = Vt + (bh * 64 + vf * 16 + lr) * 2048 + k0 + lg * 8;
            bf16x8 v0 = *(const bf16x8*)vp;
            bf16x8 v1 = *(const bf16x8*)(vp + 32);
            oacc[vf] = MFMA(pa0, v0, oacc[vf]);
            oacc[vf] = MFMA(pa1, v1, oacc[vf]);
        }
    }

    // epilogue: normalize, gate, store H[tok][h*64+dh] bf16
    const int bb = bh >> 4, h = bh & 15;
    float inv[4];
    #pragma unroll
    for (int r = 0; r < 4; ++r) inv[r] = __builtin_amdgcn_rcpf(EPS + sumw[r]);
    #pragma unroll
    for (int vf = 0; vf < 4; ++vf) {
        #pragma unroll
        for (int r = 0; r < 4; ++r) {
            const int t = q0 + lg * 4 + r;
            const int dh = vf * 16 + lr;
            const float g = b2f(Gb[(bh * 2048 + t) * 64 + dh]);
            Hb[(bb * 2048 + t) * 1024 + h * 64 + dh] = f2b(oacc[vf][r] * inv[r] * g);
        }
    }
}

// ---------------------------------------------------------------------------
// GEMM2 (bf16 MFMA): Y = Hb * Woutb^T + bout, fp32 out
// ---------------------------------------------------------------------------
__global__ __launch_bounds__(256)
void sga_gemm2(const unsigned short* __restrict__ Hb, const unsigned short* __restrict__ Wb,
               const float* __restrict__ bout, float* __restrict__ Y)
{
    __shared__ unsigned short As[128 * 40];
    __shared__ unsigned short Bs[128 * 40];
    const int tid = threadIdx.x;
    const int lane = tid & 63, w = tid >> 6;
    const int lr = lane & 15, lg = lane >> 4;
    const int wm = w & 1, wn = w >> 1;
    const int m0 = blockIdx.y * 128, n0 = blockIdx.x * 128;
    const int r0 = tid >> 2, c0 = tid & 3;

    const unsigned short* Ap = Hb + (m0 + r0) * 1024 + c0 * 8;
    const unsigned short* Bp = Wb + (n0 + r0) * 1024 + c0 * 8;
    bf16x8 pa0 = *(const bf16x8*)Ap;
    bf16x8 pa1 = *(const bf16x8*)(Ap + 64 * 1024);
    bf16x8 pb0 = *(const bf16x8*)Bp;
    bf16x8 pb1 = *(const bf16x8*)(Bp + 64 * 1024);
    unsigned short* Aw = &As[r0 * 40 + c0 * 8];
    unsigned short* Bw = &Bs[r0 * 40 + c0 * 8];

    f32x4 acc[4][4] = {};

    for (int kt = 0; kt < 32; ++kt) {
        __syncthreads();
        *(bf16x8*)Aw = pa0; *(bf16x8*)(Aw + 64 * 40) = pa1;
        *(bf16x8*)Bw = pb0; *(bf16x8*)(Bw + 64 * 40) = pb1;
        __syncthreads();
        if (kt < 31) {
            Ap += 32; Bp += 32;
            pa0 = *(const bf16x8*)Ap; pa1 = *(const bf16x8*)(Ap + 64 * 1024);
            pb0 = *(const bf16x8*)Bp; pb1 = *(const bf16x8*)(Bp + 64 * 1024);
        }
        bf16x8 af[4], bfr[4];
        #pragma unroll
        for (int i = 0; i < 4; ++i)
            af[i] = *(const bf16x8*)&As[(wm * 64 + i * 16 + lr) * 40 + lg * 8];
        #pragma unroll
        for (int i = 0; i < 4; ++i)
            bfr[i] = *(const bf16x8*)&Bs[(wn * 64 + i * 16 + lr) * 40 + lg * 8];
        #pragma unroll
        for (int mi = 0; mi < 4; ++mi)
            #pragma unroll
            for (int ni = 0; ni < 4; ++ni)
                acc[mi][ni] = MFMA(af[mi], bfr[ni], acc[mi][ni]);
    }

    #pragma unroll
    for (int mf = 0; mf < 4; ++mf) {
        const int m = m0 + wm * 64 + mf * 16 + lg * 4;
        #pragma unroll
        for (int nf = 0; nf < 4; ++nf) {
            const int n = n0 + wn * 64 + nf * 16 + lr;
            const float bz = bout[n];
            f32x4 v = acc[mf][nf];
            #pragma unroll
            for (int r = 0; r < 4; ++r)
                Y[(m + r) * 1024 + n] = v[r] + bz;
        }
    }
}

extern "C" void kernel_launch(void* const* d_in, const int* in_sizes, int n_in,
                              void* d_out, int out_size, void* d_ws, size_t ws_size,
                              hipStream_t stream) {
    const float* X    = (const float*)d_in[0];
    const float* Win  = (const float*)d_in[1];
    const float* bin  = (const float*)d_in[2];
    const float* Wout = (const float*)d_in[3];
    const float* bout = (const float*)d_in[4];
    float* Y = (float*)d_out;

    const int PER = 32 * 2048 * 64;        // 4,194,304 bf16 per Q/K/V/G tensor
    unsigned short* Qb   = (unsigned short*)d_ws;
    unsigned short* Kb   = Qb + PER;
    unsigned short* Vt   = Kb + PER;
    unsigned short* Gb   = Vt + PER;
    unsigned short* Hb   = Gb + PER;       // 4096*1024
    unsigned short* Xb   = Hb + 4096 * 1024;
    unsigned short* Winb = Xb + 4096 * 1024;
    unsigned short* Woutb= Winb + 4096 * 1024;
    float* q2s = (float*)(Woutb + 1024 * 1024);
    float* k2s = q2s + 32 * 2048;

    sga_f2b<<<1024, 256, 0, stream>>>(X, Xb, 524288);
    sga_f2b<<<1024, 256, 0, stream>>>(Win, Winb, 524288);
    sga_f2b<<<256, 256, 0, stream>>>(Wout, Woutb, 131072);
    sga_gemm1<<<dim3(32, 32), 256, 0, stream>>>(Xb, Winb, bin, Qb, Kb, Vt, Gb);
    sga_norms<<<256, 256, 0, stream>>>(Qb, Kb, q2s, k2s);
    sga_attn <<<dim3(32, 32), 256, 0, stream>>>(Qb, Kb, Vt, Gb, q2s, k2s, Hb);
    sga_gemm2<<<dim3(8, 32), 256, 0, stream>>>(Hb, Woutb, bout, Y);
}

// Round 3
// 222.315 us; speedup vs baseline: 5.5411x; 1.4750x over previous
//
#include <hip/hip_runtime.h>
#include <math.h>

#define EPS 1e-4f

// dims: B=2, T=2048, D=1024, HEADS=16, DH=64, E=4096, TOK=4096, BH=32

typedef __attribute__((ext_vector_type(8))) short bf16x8;
typedef __attribute__((ext_vector_type(4))) float f32x4;

#define MFMA(a, b, c) __builtin_amdgcn_mfma_f32_16x16x32_bf16(a, b, c, 0, 0, 0)

__device__ __forceinline__ unsigned short f2b(float f) {
    unsigned int u = __float_as_uint(f);
    u += 0x7fffu + ((u >> 16) & 1u);   // RNE
    return (unsigned short)(u >> 16);
}
__device__ __forceinline__ float b2f(unsigned short u) {
    return __uint_as_float(((unsigned int)u) << 16);
}
__device__ __forceinline__ unsigned int cvtpk(float a, float b) {
    unsigned int r;
    asm("v_cvt_pk_bf16_f32 %0, %1, %2" : "=v"(r) : "v"(a), "v"(b));
    return r;   // lo16 = bf16(a), hi16 = bf16(b)
}

// ---------------------------------------------------------------------------
// fp32 -> bf16 convert (vectorized, grid-stride). n8 = elements/8.
// ---------------------------------------------------------------------------
__global__ __launch_bounds__(256)
void sga_f2b(const float* __restrict__ src, unsigned short* __restrict__ dst, int n8) {
    int i = blockIdx.x * 256 + threadIdx.x;
    const int stride = gridDim.x * 256;
    for (; i < n8; i += stride) {
        const float4* s = (const float4*)src + i * 2;
        float4 a = s[0], b = s[1];
        uint4 o;
        o.x = (unsigned)f2b(a.x) | ((unsigned)f2b(a.y) << 16);
        o.y = (unsigned)f2b(a.z) | ((unsigned)f2b(a.w) << 16);
        o.z = (unsigned)f2b(b.x) | ((unsigned)f2b(b.y) << 16);
        o.w = (unsigned)f2b(b.z) | ((unsigned)f2b(b.w) << 16);
        *((uint4*)dst + i) = o;
    }
}

// ---------------------------------------------------------------------------
// GEMM1 (bf16 MFMA, 128x128 tile, BK=32): P = Xb * Winb^T + bin, scattered:
//   e = h*256 + part*64 + j ; part 0=Q,1=K,3=G natural [bh][t][64] bf16
//   part 2=V transposed [bh][64][t] bf16
// ---------------------------------------------------------------------------
__global__ __launch_bounds__(256)
void sga_gemm1(const unsigned short* __restrict__ Xb, const unsigned short* __restrict__ Wb,
               const float* __restrict__ bin,
               unsigned short* __restrict__ Qb, unsigned short* __restrict__ Kb,
               unsigned short* __restrict__ Vt, unsigned short* __restrict__ Gb)
{
    __shared__ unsigned short As[128 * 40];
    __shared__ unsigned short Bs[128 * 40];
    const int tid = threadIdx.x;
    const int lane = tid & 63, w = tid >> 6;
    const int lr = lane & 15, lg = lane >> 4;
    const int wm = w & 1, wn = w >> 1;
    const int m0 = blockIdx.y * 128, n0 = blockIdx.x * 128;
    const int r0 = tid >> 2, c0 = tid & 3;

    const unsigned short* Ap = Xb + (m0 + r0) * 1024 + c0 * 8;
    const unsigned short* Bp = Wb + (n0 + r0) * 1024 + c0 * 8;
    bf16x8 pa0 = *(const bf16x8*)Ap;
    bf16x8 pa1 = *(const bf16x8*)(Ap + 64 * 1024);
    bf16x8 pb0 = *(const bf16x8*)Bp;
    bf16x8 pb1 = *(const bf16x8*)(Bp + 64 * 1024);
    unsigned short* Aw = &As[r0 * 40 + c0 * 8];
    unsigned short* Bw = &Bs[r0 * 40 + c0 * 8];

    f32x4 acc[4][4] = {};

    for (int kt = 0; kt < 32; ++kt) {
        __syncthreads();
        *(bf16x8*)Aw = pa0; *(bf16x8*)(Aw + 64 * 40) = pa1;
        *(bf16x8*)Bw = pb0; *(bf16x8*)(Bw + 64 * 40) = pb1;
        __syncthreads();
        if (kt < 31) {
            Ap += 32; Bp += 32;
            pa0 = *(const bf16x8*)Ap; pa1 = *(const bf16x8*)(Ap + 64 * 1024);
            pb0 = *(const bf16x8*)Bp; pb1 = *(const bf16x8*)(Bp + 64 * 1024);
        }
        bf16x8 af[4], bfr[4];
        #pragma unroll
        for (int i = 0; i < 4; ++i)
            af[i] = *(const bf16x8*)&As[(wm * 64 + i * 16 + lr) * 40 + lg * 8];
        #pragma unroll
        for (int i = 0; i < 4; ++i)
            bfr[i] = *(const bf16x8*)&Bs[(wn * 64 + i * 16 + lr) * 40 + lg * 8];
        #pragma unroll
        for (int mi = 0; mi < 4; ++mi)
            #pragma unroll
            for (int ni = 0; ni < 4; ++ni)
                acc[mi][ni] = MFMA(af[mi], bfr[ni], acc[mi][ni]);
    }

    // epilogue scatter
    const int bb = m0 >> 11;
    #pragma unroll
    for (int mf = 0; mf < 4; ++mf) {
        const int tbase = m0 + wm * 64 + mf * 16 + lg * 4;
        const int tloc = tbase & 2047;
        #pragma unroll
        for (int nf = 0; nf < 4; ++nf) {
            const int n = n0 + wn * 64 + nf * 16 + lr;
            const int h = n >> 8, cc = n & 255;
            const int part = cc >> 6, j = cc & 63;
            const int bh = bb * 16 + h;
            const float bz = bin[n];
            f32x4 v = acc[mf][nf];
            unsigned short e0 = f2b(v[0] + bz), e1 = f2b(v[1] + bz),
                           e2 = f2b(v[2] + bz), e3 = f2b(v[3] + bz);
            if (part == 2) {
                ushort4 pk = make_ushort4(e0, e1, e2, e3);
                *(ushort4*)&Vt[(bh * 64 + j) * 2048 + tloc] = pk;
            } else {
                unsigned short* dst = (part == 0) ? Qb : ((part == 1) ? Kb : Gb);
                unsigned short vv[4] = {e0, e1, e2, e3};
                #pragma unroll
                for (int r = 0; r < 4; ++r)
                    dst[(bh * 2048 + tloc + r) * 64 + j] = vv[r];
            }
        }
    }
}

// ---------------------------------------------------------------------------
// fp32 row norms of the bf16-rounded Q,K (self-consistent with MFMA QK^T)
// ---------------------------------------------------------------------------
__global__ __launch_bounds__(256)
void sga_norms(const unsigned short* __restrict__ Qb, const unsigned short* __restrict__ Kb,
               float* __restrict__ q2s, float* __restrict__ k2s)
{
    const int idx = blockIdx.x * 256 + threadIdx.x;  // 0..65535 = bh*2048+t
    const unsigned short* q = Qb + idx * 64;
    const unsigned short* k = Kb + idx * 64;
    float sq = 0.f, sk = 0.f;
    #pragma unroll
    for (int c = 0; c < 8; ++c) {
        bf16x8 a = *(const bf16x8*)(q + c * 8);
        bf16x8 b = *(const bf16x8*)(k + c * 8);
        #pragma unroll
        for (int e = 0; e < 8; ++e) {
            float f = b2f((unsigned short)a[e]); sq += f * f;
            float g = b2f((unsigned short)b[e]); sk += g * g;
        }
    }
    q2s[idx] = sq;
    k2s[idx] = sk;
}

// ---------------------------------------------------------------------------
// Attention, swapped-QK^T MFMA. Block = 4 waves, 32 q-rows per wave.
// Per kt: K prefetched (kt+1 issued after QK^T), V issued at top (consumed
// after LDS roundtrip). Weights w = 1/max(d2,1e-8) (sqrt-free). W^T stash via
// packed ds_write_b64 into per-wave LDS slab, re-read as PV A-fragments.
// No __syncthreads anywhere.
// ---------------------------------------------------------------------------
__global__ __launch_bounds__(256)
void sga_attn(const unsigned short* __restrict__ Qb, const unsigned short* __restrict__ Kb,
              const unsigned short* __restrict__ Vt, const unsigned short* __restrict__ Gb,
              const float* __restrict__ q2s, const float* __restrict__ k2s,
              unsigned short* __restrict__ Hb)
{
    __shared__ unsigned short Wlds[4 * 32 * 72];
    const int tid = threadIdx.x;
    const int lane = tid & 63, w = tid >> 6;
    const int lr = lane & 15, lg = lane >> 4;
    const int bh = blockIdx.y;
    const int q0 = blockIdx.x * 128 + w * 32;
    unsigned short* wl = &Wlds[w * 32 * 72];

    // Q fragments (B-operand): Q[q = q0+g*16+lr][d = h*32 + lg*8 + e]
    bf16x8 qf[2][2];
    #pragma unroll
    for (int g = 0; g < 2; ++g) {
        const unsigned short* qp = Qb + (bh * 2048 + q0 + g * 16 + lr) * 64 + lg * 8;
        qf[g][0] = *(const bf16x8*)qp;
        qf[g][1] = *(const bf16x8*)(qp + 32);
    }
    float q2v[2];
    q2v[0] = q2s[bh * 2048 + q0 + lr];
    q2v[1] = q2s[bh * 2048 + q0 + 16 + lr];

    f32x4 oacc[2][4] = {};
    float sumw[2] = {0.f, 0.f};

    // prefetch K fragments for kt=0 (A-operand): K[k = nf*16+lr][d]
    bf16x8 kf[4][2];
    #pragma unroll
    for (int nf = 0; nf < 4; ++nf) {
        const unsigned short* kp = Kb + (bh * 2048 + nf * 16 + lr) * 64 + lg * 8;
        kf[nf][0] = *(const bf16x8*)kp;
        kf[nf][1] = *(const bf16x8*)(kp + 32);
    }

    for (int kt = 0; kt < 32; ++kt) {
        const int k0 = kt * 64;

        // V loads for this kt (B-operand): V[dh = vf*16+lr][k = lg*8+e]
        bf16x8 vr[4][2];
        #pragma unroll
        for (int vf = 0; vf < 4; ++vf) {
            const unsigned short* vp = Vt + (bh * 64 + vf * 16 + lr) * 2048 + k0 + lg * 8;
            vr[vf][0] = *(const bf16x8*)vp;
            vr[vf][1] = *(const bf16x8*)(vp + 32);
        }
        f32x4 k2v[4];
        #pragma unroll
        for (int nf = 0; nf < 4; ++nf)
            k2v[nf] = *(const f32x4*)&k2s[bh * 2048 + k0 + nf * 16 + lg * 4];

        // QK^T swapped: sa[g][nf] = S^T tile, lane holds S[k=nf*16+lg*4+r][q=g*16+lr]
        f32x4 sa[2][4] = {};
        __builtin_amdgcn_s_setprio(1);
        #pragma unroll
        for (int nf = 0; nf < 4; ++nf) {
            #pragma unroll
            for (int g = 0; g < 2; ++g) {
                sa[g][nf] = MFMA(kf[nf][0], qf[g][0], sa[g][nf]);
                sa[g][nf] = MFMA(kf[nf][1], qf[g][1], sa[g][nf]);
            }
        }
        __builtin_amdgcn_s_setprio(0);

        // prefetch K fragments for kt+1 (in flight across weights+LDS+PV)
        if (kt < 31) {
            #pragma unroll
            for (int nf = 0; nf < 4; ++nf) {
                const unsigned short* kp =
                    Kb + (bh * 2048 + k0 + 64 + nf * 16 + lr) * 64 + lg * 8;
                kf[nf][0] = *(const bf16x8*)kp;
                kf[nf][1] = *(const bf16x8*)(kp + 32);
            }
        }

        // Shepard weights (sqrt-free), pack bf16, stash W^T[q][k] in LDS
        float rs[2] = {0.f, 0.f};
        #pragma unroll
        for (int g = 0; g < 2; ++g) {
            #pragma unroll
            for (int nf = 0; nf < 4; ++nf) {
                float wv[4];
                #pragma unroll
                for (int r = 0; r < 4; ++r) {
                    float d2 = fmaf(-2.0f, sa[g][nf][r], q2v[g] + k2v[nf][r]);
                    d2 = fmaxf(d2, 1e-8f);
                    wv[r] = __builtin_amdgcn_rcpf(d2);
                    rs[g] += wv[r];
                }
                uint2 pk;
                pk.x = cvtpk(wv[0], wv[1]);
                pk.y = cvtpk(wv[2], wv[3]);
                *(uint2*)&wl[(g * 16 + lr) * 72 + nf * 16 + lg * 4] = pk;
            }
        }
        #pragma unroll
        for (int g = 0; g < 2; ++g) {
            rs[g] += __shfl_xor(rs[g], 16, 64);
            rs[g] += __shfl_xor(rs[g], 32, 64);
            sumw[g] += rs[g];
        }

        // PV: A = W fragments from LDS, B = V
        bf16x8 pa[2][2];
        #pragma unroll
        for (int g = 0; g < 2; ++g) {
            pa[g][0] = *(const bf16x8*)&wl[(g * 16 + lr) * 72 + lg * 8];
            pa[g][1] = *(const bf16x8*)&wl[(g * 16 + lr) * 72 + 32 + lg * 8];
        }
        __builtin_amdgcn_s_setprio(1);
        #pragma unroll
        for (int vf = 0; vf < 4; ++vf) {
            #pragma unroll
            for (int g = 0; g < 2; ++g) {
                oacc[g][vf] = MFMA(pa[g][0], vr[vf][0], oacc[g][vf]);
                oacc[g][vf] = MFMA(pa[g][1], vr[vf][1], oacc[g][vf]);
            }
        }
        __builtin_amdgcn_s_setprio(0);
    }

    // epilogue: normalize, gate, store H[tok][h*64+dh] bf16
    const int bb = bh >> 4, h = bh & 15;
    #pragma unroll
    for (int g = 0; g < 2; ++g) {
        float invv[4];
        #pragma unroll
        for (int r = 0; r < 4; ++r)
            invv[r] = __builtin_amdgcn_rcpf(EPS + __shfl(sumw[g], lg * 4 + r, 64));
        #pragma unroll
        for (int vf = 0; vf < 4; ++vf) {
            #pragma unroll
            for (int r = 0; r < 4; ++r) {
                const int t = q0 + g * 16 + lg * 4 + r;
                const int dh = vf * 16 + lr;
                const float gv = b2f(Gb[(bh * 2048 + t) * 64 + dh]);
                Hb[(bb * 2048 + t) * 1024 + h * 64 + dh] =
                    f2b(oacc[g][vf][r] * invv[r] * gv);
            }
        }
    }
}

// ---------------------------------------------------------------------------
// GEMM2 (bf16 MFMA): Y = Hb * Woutb^T + bout, fp32 out
// ---------------------------------------------------------------------------
__global__ __launch_bounds__(256)
void sga_gemm2(const unsigned short* __restrict__ Hb, const unsigned short* __restrict__ Wb,
               const float* __restrict__ bout, float* __restrict__ Y)
{
    __shared__ unsigned short As[128 * 40];
    __shared__ unsigned short Bs[128 * 40];
    const int tid = threadIdx.x;
    const int lane = tid & 63, w = tid >> 6;
    const int lr = lane & 15, lg = lane >> 4;
    const int wm = w & 1, wn = w >> 1;
    const int m0 = blockIdx.y * 128, n0 = blockIdx.x * 128;
    const int r0 = tid >> 2, c0 = tid & 3;

    const unsigned short* Ap = Hb + (m0 + r0) * 1024 + c0 * 8;
    const unsigned short* Bp = Wb + (n0 + r0) * 1024 + c0 * 8;
    bf16x8 pa0 = *(const bf16x8*)Ap;
    bf16x8 pa1 = *(const bf16x8*)(Ap + 64 * 1024);
    bf16x8 pb0 = *(const bf16x8*)Bp;
    bf16x8 pb1 = *(const bf16x8*)(Bp + 64 * 1024);
    unsigned short* Aw = &As[r0 * 40 + c0 * 8];
    unsigned short* Bw = &Bs[r0 * 40 + c0 * 8];

    f32x4 acc[4][4] = {};

    for (int kt = 0; kt < 32; ++kt) {
        __syncthreads();
        *(bf16x8*)Aw = pa0; *(bf16x8*)(Aw + 64 * 40) = pa1;
        *(bf16x8*)Bw = pb0; *(bf16x8*)(Bw + 64 * 40) = pb1;
        __syncthreads();
        if (kt < 31) {
            Ap += 32; Bp += 32;
            pa0 = *(const bf16x8*)Ap; pa1 = *(const bf16x8*)(Ap + 64 * 1024);
            pb0 = *(const bf16x8*)Bp; pb1 = *(const bf16x8*)(Bp + 64 * 1024);
        }
        bf16x8 af[4], bfr[4];
        #pragma unroll
        for (int i = 0; i < 4; ++i)
            af[i] = *(const bf16x8*)&As[(wm * 64 + i * 16 + lr) * 40 + lg * 8];
        #pragma unroll
        for (int i = 0; i < 4; ++i)
            bfr[i] = *(const bf16x8*)&Bs[(wn * 64 + i * 16 + lr) * 40 + lg * 8];
        #pragma unroll
        for (int mi = 0; mi < 4; ++mi)
            #pragma unroll
            for (int ni = 0; ni < 4; ++ni)
                acc[mi][ni] = MFMA(af[mi], bfr[ni], acc[mi][ni]);
    }

    #pragma unroll
    for (int mf = 0; mf < 4; ++mf) {
        const int m = m0 + wm * 64 + mf * 16 + lg * 4;
        #pragma unroll
        for (int nf = 0; nf < 4; ++nf) {
            const int n = n0 + wn * 64 + nf * 16 + lr;
            const float bz = bout[n];
            f32x4 v = acc[mf][nf];
            #pragma unroll
            for (int r = 0; r < 4; ++r)
                Y[(m + r) * 1024 + n] = v[r] + bz;
        }
    }
}

extern "C" void kernel_launch(void* const* d_in, const int* in_sizes, int n_in,
                              void* d_out, int out_size, void* d_ws, size_t ws_size,
                              hipStream_t stream) {
    const float* X    = (const float*)d_in[0];
    const float* Win  = (const float*)d_in[1];
    const float* bin  = (const float*)d_in[2];
    const float* Wout = (const float*)d_in[3];
    const float* bout = (const float*)d_in[4];
    float* Y = (float*)d_out;

    const int PER = 32 * 2048 * 64;        // 4,194,304 bf16 per Q/K/V/G tensor
    unsigned short* Qb   = (unsigned short*)d_ws;
    unsigned short* Kb   = Qb + PER;
    unsigned short* Vt   = Kb + PER;
    unsigned short* Gb   = Vt + PER;
    unsigned short* Hb   = Gb + PER;       // 4096*1024
    unsigned short* Xb   = Hb + 4096 * 1024;
    unsigned short* Winb = Xb + 4096 * 1024;
    unsigned short* Woutb= Winb + 4096 * 1024;
    float* q2s = (float*)(Woutb + 1024 * 1024);
    float* k2s = q2s + 32 * 2048;

    sga_f2b<<<1024, 256, 0, stream>>>(X, Xb, 524288);
    sga_f2b<<<1024, 256, 0, stream>>>(Win, Winb, 524288);
    sga_f2b<<<256, 256, 0, stream>>>(Wout, Woutb, 131072);
    sga_gemm1<<<dim3(32, 32), 256, 0, stream>>>(Xb, Winb, bin, Qb, Kb, Vt, Gb);
    sga_norms<<<256, 256, 0, stream>>>(Qb, Kb, q2s, k2s);
    sga_attn <<<dim3(16, 32), 256, 0, stream>>>(Qb, Kb, Vt, Gb, q2s, k2s, Hb);
    sga_gemm2<<<dim3(8, 32), 256, 0, stream>>>(Hb, Woutb, bout, Y);
}